// Round 1
// baseline (334.013 us; speedup 1.0000x reference)
//
#include <hip/hip_runtime.h>
#include <hip/hip_bf16.h>

// Head: k/q/v projection + causal softmax attention, single head.
// B=8, T=4096, C=1024, H=64. All inputs fp32; output fp32.
// Plan:
//   k0: wT[n][k] bf16 transpose of [Wq|Wk|Wv]  (q cols pre-scaled by 0.125*log2e)
//   k1: qkv projection via mfma_f32_16x16x32_bf16 -> q_ws, k_ws (row-major), vT (transposed)
//   k2: flash attention, 1 wave = 16 q rows, KV tiles of 32, swapped-operand MFMA.

#define HS 64
#define NE 1024
#define NB 8
#define TS 4096
#define NROW (NB * TS)  // 32768

typedef __attribute__((ext_vector_type(4))) float  f32x4;
typedef __attribute__((ext_vector_type(8))) short  s16x8;  // bf16x8 MFMA fragment
typedef __attribute__((ext_vector_type(4))) float  vfloat4;

__device__ __forceinline__ unsigned short f2bf(float x) {
  unsigned u = __builtin_bit_cast(unsigned, x);
  u += 0x7fffu + ((u >> 16) & 1u);          // round-to-nearest-even
  return (unsigned short)(u >> 16);
}
__device__ __forceinline__ unsigned pkbf(float lo, float hi) {
  return (unsigned)f2bf(lo) | ((unsigned)f2bf(hi) << 16);
}

union ABFrag { s16x8 v; unsigned d[4]; };

// ---------------- kernel 0: weight transpose+cast ----------------
// wT[n][k], n in [0,192): n<64 -> Wq (scaled), 64..127 -> Wk, 128..191 -> Wv
__global__ __launch_bounds__(256) void wt_kernel(const float* __restrict__ Wk,
                                                 const float* __restrict__ Wq,
                                                 const float* __restrict__ Wv,
                                                 unsigned short* __restrict__ wT) {
  int gid = blockIdx.x * 256 + threadIdx.x;   // 0..196607
  int n = gid >> 10, k = gid & 1023;
  const float* W = (n < 64) ? Wq : (n < 128) ? Wk : Wv;
  float s = (n < 64) ? 0.18033688011112042f : 1.0f;  // 0.125 * log2(e)
  wT[gid] = f2bf(W[k * 64 + (n & 63)] * s);
}

// ---------------- kernel 1: fused QKV projection ----------------
// Block = 4 waves, 64 rows of x. Wave w: rows m0+16w .. +15, all 192 cols.
// A-frag: lane row = l&15, k = (l>>4)*8+j (8 fp32 from x, cast to bf16).
// B-frag: lane col = l&15, k = (l>>4)*8+j (16B load from wT).
// D: col = l&15, row = (l>>4)*4 + j.
__global__ __launch_bounds__(256) void qkv_kernel(const float* __restrict__ x,
                                                  const unsigned short* __restrict__ wT,
                                                  unsigned short* __restrict__ q_ws,
                                                  unsigned short* __restrict__ k_ws,
                                                  unsigned short* __restrict__ vT) {
  const int wv = threadIdx.x >> 6, lane = threadIdx.x & 63;
  const int g = lane >> 4, nn = lane & 15;
  const int m0 = blockIdx.x * 64 + wv * 16;
  const int arow = m0 + nn;                      // this lane's A row

  f32x4 acc[12];
#pragma unroll
  for (int i = 0; i < 12; ++i) acc[i] = f32x4{0.f, 0.f, 0.f, 0.f};

  const float* xrow = x + (size_t)arow * NE;
  for (int kc = 0; kc < NE; kc += 32) {
    const vfloat4* xp = (const vfloat4*)(xrow + kc + 8 * g);
    vfloat4 a0 = xp[0], a1 = xp[1];
    ABFrag af;
    af.d[0] = pkbf(a0.x, a0.y);
    af.d[1] = pkbf(a0.z, a0.w);
    af.d[2] = pkbf(a1.x, a1.y);
    af.d[3] = pkbf(a1.z, a1.w);
#pragma unroll
    for (int i = 0; i < 12; ++i) {
      s16x8 bf = *(const s16x8*)(wT + (size_t)(16 * i + nn) * NE + kc + 8 * g);
      acc[i] = __builtin_amdgcn_mfma_f32_16x16x32_bf16(af.v, bf, acc[i], 0, 0, 0);
    }
  }

  // epilogue: D row = m0 + 4g + j, col = 16i + nn
  const int rbase = m0 + 4 * g;
#pragma unroll
  for (int i = 0; i < 12; ++i) {
    const int c = 16 * i + nn;
#pragma unroll
    for (int j = 0; j < 4; ++j) {
      const int r = rbase + j;                  // global M row = b*T + t
      const unsigned short h = f2bf(acc[i][j]);
      if (c < 64) {
        q_ws[(size_t)r * HS + c] = h;
      } else if (c < 128) {
        k_ws[(size_t)r * HS + (c - 64)] = h;
      } else {
        const int b = r >> 12, t = r & 4095;
        vT[((size_t)(b * HS + (c - 128))) * TS + t] = h;
      }
    }
  }
}

// ---------------- kernel 2: causal flash attention ----------------
// 1 wave = one 16-row Q tile. KV tile = 32 (two 16x16 S^T tiles).
// S^T = mfma(A=K-rows, B=Q^T): lane holds scores for q-col nn, kv rows 4g+j (per tile).
// O^T += mfma(A=V^T-frag, B=P^T-frag): lane holds O[h=16i+4g+j][q=nn].
__global__ __launch_bounds__(256) void attn_kernel(const unsigned short* __restrict__ q_ws,
                                                   const unsigned short* __restrict__ k_ws,
                                                   const unsigned short* __restrict__ vT,
                                                   float* __restrict__ out) {
  const int wv = threadIdx.x >> 6, lane = threadIdx.x & 63;
  const int g = lane >> 4, nn = lane & 15;

  // wave -> (batch, q-tile), long/short interleaved for balance
  const int wglob = blockIdx.x * 4 + wv;        // 0..2047
  const int idx0 = wglob >> 3;                  // 0..255
  const int b = wglob & 7;
  const int hf = idx0 >> 1;
  const int ti = (idx0 & 1) ? (255 - hf) : hf;
  const int t0 = ti * 16;
  const int tg = t0 + nn;                       // this lane's q row

  const unsigned short* qb = q_ws + ((size_t)(b * TS + tg)) * HS;
  const s16x8 qf0 = *(const s16x8*)(qb + 8 * g);
  const s16x8 qf1 = *(const s16x8*)(qb + 32 + 8 * g);

  const unsigned short* kptr = k_ws + (size_t)b * TS * HS;
  const unsigned short* vptr = vT + (size_t)b * HS * TS;

  f32x4 o[4];
#pragma unroll
  for (int i = 0; i < 4; ++i) o[i] = f32x4{0.f, 0.f, 0.f, 0.f};
  float m_run = -1e30f, l_run = 0.f;

  const int nt = (t0 + 16 + 31) >> 5;
  for (int it = 0; it < nt; ++it) {
    const int s0 = it * 32;
    // --- QK^T (swapped): two 16x16 S^T tiles
    const unsigned short* k0 = kptr + (size_t)(s0 + nn) * HS;
    const unsigned short* k1 = kptr + (size_t)(s0 + 16 + nn) * HS;
    s16x8 ka0 = *(const s16x8*)(k0 + 8 * g);
    s16x8 ka1 = *(const s16x8*)(k0 + 32 + 8 * g);
    s16x8 kb0 = *(const s16x8*)(k1 + 8 * g);
    s16x8 kb1 = *(const s16x8*)(k1 + 32 + 8 * g);
    f32x4 st0 = f32x4{0.f, 0.f, 0.f, 0.f};
    f32x4 st1 = f32x4{0.f, 0.f, 0.f, 0.f};
    st0 = __builtin_amdgcn_mfma_f32_16x16x32_bf16(ka0, qf0, st0, 0, 0, 0);
    st0 = __builtin_amdgcn_mfma_f32_16x16x32_bf16(ka1, qf1, st0, 0, 0, 0);
    st1 = __builtin_amdgcn_mfma_f32_16x16x32_bf16(kb0, qf0, st1, 0, 0, 0);
    st1 = __builtin_amdgcn_mfma_f32_16x16x32_bf16(kb1, qf1, st1, 0, 0, 0);

    // --- causal mask: score (s = s0 + 16t + 4g + j, q = tg)
    const int sb0 = s0 + 4 * g, sb1 = s0 + 16 + 4 * g;
#pragma unroll
    for (int j = 0; j < 4; ++j) {
      if (sb0 + j > tg) st0[j] = -1e30f;
      if (sb1 + j > tg) st1[j] = -1e30f;
    }

    // --- online softmax (row = q = nn; partners at lane^16, lane^32)
    float mx = fmaxf(fmaxf(fmaxf(st0[0], st0[1]), fmaxf(st0[2], st0[3])),
                     fmaxf(fmaxf(st1[0], st1[1]), fmaxf(st1[2], st1[3])));
    mx = fmaxf(mx, __shfl_xor(mx, 16, 64));
    mx = fmaxf(mx, __shfl_xor(mx, 32, 64));
    const float m_new = fmaxf(m_run, mx);
    const float f = __builtin_amdgcn_exp2f(m_run - m_new);
    float p0[4], p1[4], sm = 0.f;
#pragma unroll
    for (int j = 0; j < 4; ++j) { p0[j] = __builtin_amdgcn_exp2f(st0[j] - m_new); sm += p0[j]; }
#pragma unroll
    for (int j = 0; j < 4; ++j) { p1[j] = __builtin_amdgcn_exp2f(st1[j] - m_new); sm += p1[j]; }
    sm += __shfl_xor(sm, 16, 64);
    sm += __shfl_xor(sm, 32, 64);
    l_run = l_run * f + sm;
    m_run = m_new;
#pragma unroll
    for (int i = 0; i < 4; ++i) {
#pragma unroll
      for (int j = 0; j < 4; ++j) o[i][j] *= f;
    }

    // --- relayout P -> P^T B-frag (lane needs s = 8g..8g+7 at col nn)
    const unsigned d00 = pkbf(p0[0], p0[1]), d01 = pkbf(p0[2], p0[3]);
    const unsigned d10 = pkbf(p1[0], p1[1]), d11 = pkbf(p1[2], p1[3]);
    const int laneA = nn | (((2 * g) & 3) << 4);
    const int laneB = nn | (((2 * g + 1) & 3) << 4);
    const unsigned eA0t0 = (unsigned)__shfl((int)d00, laneA, 64);
    const unsigned eA0t1 = (unsigned)__shfl((int)d10, laneA, 64);
    const unsigned eA1t0 = (unsigned)__shfl((int)d01, laneA, 64);
    const unsigned eA1t1 = (unsigned)__shfl((int)d11, laneA, 64);
    const unsigned eB0t0 = (unsigned)__shfl((int)d00, laneB, 64);
    const unsigned eB0t1 = (unsigned)__shfl((int)d10, laneB, 64);
    const unsigned eB1t0 = (unsigned)__shfl((int)d01, laneB, 64);
    const unsigned eB1t1 = (unsigned)__shfl((int)d11, laneB, 64);
    const bool hi = (g >= 2);                    // s >= 16 -> tile 1
    ABFrag pb;
    pb.d[0] = hi ? eA0t1 : eA0t0;
    pb.d[1] = hi ? eA1t1 : eA1t0;
    pb.d[2] = hi ? eB0t1 : eB0t0;
    pb.d[3] = hi ? eB1t1 : eB1t0;

    // --- PV (swapped): O^T += V^T-frag * P^T-frag, 4 h-tiles
#pragma unroll
    for (int i = 0; i < 4; ++i) {
      s16x8 vf = *(const s16x8*)(vptr + (size_t)(16 * i + nn) * TS + s0 + 8 * g);
      o[i] = __builtin_amdgcn_mfma_f32_16x16x32_bf16(vf, pb.v, o[i], 0, 0, 0);
    }
  }

  // --- epilogue: out[b][tg][h] = O^T[h][q=nn] / l
  const float inv = 1.0f / l_run;
  float* ob = out + ((size_t)(b * TS + tg)) * HS;
#pragma unroll
  for (int i = 0; i < 4; ++i) {
#pragma unroll
    for (int j = 0; j < 4; ++j) ob[16 * i + 4 * g + j] = o[i][j] * inv;
  }
}

extern "C" void kernel_launch(void* const* d_in, const int* in_sizes, int n_in,
                              void* d_out, int out_size, void* d_ws, size_t ws_size,
                              hipStream_t stream) {
  const float* x  = (const float*)d_in[0];
  const float* Wk = (const float*)d_in[1];
  const float* Wq = (const float*)d_in[2];
  const float* Wv = (const float*)d_in[3];
  float* out = (float*)d_out;

  // workspace carve (bf16): wT 192*1024, q/k 32768*64 each, vT 8*64*4096
  unsigned short* wT   = (unsigned short*)d_ws;
  unsigned short* q_ws = wT + 192 * 1024;
  unsigned short* k_ws = q_ws + (size_t)NROW * HS;
  unsigned short* vT   = k_ws + (size_t)NROW * HS;

  wt_kernel<<<dim3(768), dim3(256), 0, stream>>>(Wk, Wq, Wv, wT);
  qkv_kernel<<<dim3(NROW / 64), dim3(256), 0, stream>>>(x, wT, q_ws, k_ws, vT);
  attn_kernel<<<dim3(512), dim3(256), 0, stream>>>(q_ws, k_ws, vT, out);
}

// Round 3
// 304.739 us; speedup vs baseline: 1.0961x; 1.0961x over previous
//
#include <hip/hip_runtime.h>
#include <hip/hip_bf16.h>

// Head: k/q/v projection + causal softmax attention, single head.
// B=8, T=4096, C=1024, H=64. All inputs fp32; output fp32.
//   k0: wT[n][k] bf16 transpose of [Wq|Wk|Wv]  (q cols pre-scaled by 0.125*log2e)
//   k1: qkv projection via mfma_f32_16x16x32_bf16; 32 rows/wave, x prefetch
//   k2: flash attention; 1 block (4 waves) per 16-row q-tile; waves split the
//       causal KV range 4-way (strided), partials merged in LDS (flash-decode
//       style split-K inside the block). Raises occupancy 2048->8192 waves.

#define HS 64
#define NE 1024
#define NB 8
#define TS 4096
#define NROW (NB * TS)  // 32768

typedef __attribute__((ext_vector_type(4))) float  f32x4;
typedef __attribute__((ext_vector_type(8))) short  s16x8;  // bf16x8 MFMA fragment
typedef __attribute__((ext_vector_type(4))) float  vfloat4;

__device__ __forceinline__ unsigned short f2bf(float x) {
  unsigned u = __builtin_bit_cast(unsigned, x);
  u += 0x7fffu + ((u >> 16) & 1u);          // round-to-nearest-even
  return (unsigned short)(u >> 16);
}
__device__ __forceinline__ unsigned pkbf(float lo, float hi) {
  return (unsigned)f2bf(lo) | ((unsigned)f2bf(hi) << 16);
}

union ABFrag { s16x8 v; unsigned d[4]; };

// ---------------- kernel 0: weight transpose+cast ----------------
__global__ __launch_bounds__(256) void wt_kernel(const float* __restrict__ Wk,
                                                 const float* __restrict__ Wq,
                                                 const float* __restrict__ Wv,
                                                 unsigned short* __restrict__ wT) {
  int gid = blockIdx.x * 256 + threadIdx.x;   // 0..196607
  int n = gid >> 10, k = gid & 1023;
  const float* W = (n < 64) ? Wq : (n < 128) ? Wk : Wv;
  float s = (n < 64) ? 0.18033688011112042f : 1.0f;  // 0.125 * log2(e)
  wT[gid] = f2bf(W[k * 64 + (n & 63)] * s);
}

// ---------------- kernel 1: fused QKV projection ----------------
// Block = 4 waves; wave owns 32 rows (two 16-row A-frags sharing the 12
// B-frag loads per 32-K chunk). Manual prefetch of next x chunk.
__global__ __launch_bounds__(256) void qkv_kernel(const float* __restrict__ x,
                                                  const unsigned short* __restrict__ wT,
                                                  unsigned short* __restrict__ q_ws,
                                                  unsigned short* __restrict__ k_ws,
                                                  unsigned short* __restrict__ vT) {
  const int wv = threadIdx.x >> 6, lane = threadIdx.x & 63;
  const int g = lane >> 4, nn = lane & 15;
  const int m0 = blockIdx.x * 128 + wv * 32;

  f32x4 acc[2][12];
#pragma unroll
  for (int r = 0; r < 2; ++r)
#pragma unroll
    for (int i = 0; i < 12; ++i) acc[r][i] = f32x4{0.f, 0.f, 0.f, 0.f};

  const float* xr0 = x + (size_t)(m0 + nn) * NE;
  const float* xr1 = x + (size_t)(m0 + 16 + nn) * NE;

  vfloat4 n00 = ((const vfloat4*)(xr0 + 8 * g))[0];
  vfloat4 n01 = ((const vfloat4*)(xr0 + 8 * g))[1];
  vfloat4 n10 = ((const vfloat4*)(xr1 + 8 * g))[0];
  vfloat4 n11 = ((const vfloat4*)(xr1 + 8 * g))[1];

  for (int kc = 0; kc < NE; kc += 32) {
    vfloat4 c00 = n00, c01 = n01, c10 = n10, c11 = n11;
    if (kc + 32 < NE) {
      const vfloat4* p0 = (const vfloat4*)(xr0 + kc + 32 + 8 * g);
      const vfloat4* p1 = (const vfloat4*)(xr1 + kc + 32 + 8 * g);
      n00 = p0[0]; n01 = p0[1]; n10 = p1[0]; n11 = p1[1];
    }
    ABFrag a0, a1;
    a0.d[0] = pkbf(c00.x, c00.y); a0.d[1] = pkbf(c00.z, c00.w);
    a0.d[2] = pkbf(c01.x, c01.y); a0.d[3] = pkbf(c01.z, c01.w);
    a1.d[0] = pkbf(c10.x, c10.y); a1.d[1] = pkbf(c10.z, c10.w);
    a1.d[2] = pkbf(c11.x, c11.y); a1.d[3] = pkbf(c11.z, c11.w);
#pragma unroll
    for (int i = 0; i < 12; ++i) {
      s16x8 bf = *(const s16x8*)(wT + (size_t)(16 * i + nn) * NE + kc + 8 * g);
      acc[0][i] = __builtin_amdgcn_mfma_f32_16x16x32_bf16(a0.v, bf, acc[0][i], 0, 0, 0);
      acc[1][i] = __builtin_amdgcn_mfma_f32_16x16x32_bf16(a1.v, bf, acc[1][i], 0, 0, 0);
    }
  }

  // epilogue: D row = m0 + 16r + 4g + j, col = 16i + nn
#pragma unroll
  for (int r = 0; r < 2; ++r) {
    const int rbase = m0 + 16 * r + 4 * g;
#pragma unroll
    for (int i = 0; i < 12; ++i) {
      const int c = 16 * i + nn;
#pragma unroll
      for (int j = 0; j < 4; ++j) {
        const int rr = rbase + j;
        const unsigned short h = f2bf(acc[r][i][j]);
        if (c < 64) {
          q_ws[(size_t)rr * HS + c] = h;
        } else if (c < 128) {
          k_ws[(size_t)rr * HS + (c - 64)] = h;
        } else {
          const int b = rr >> 12, t = rr & 4095;
          vT[((size_t)(b * HS + (c - 128))) * TS + t] = h;
        }
      }
    }
  }
}

// ---------------- kernel 2: causal flash attention, intra-block KV split ----
// Block (4 waves) owns one (b, ti) 16-row q-tile. Wave wv processes KV tiles
// it = wv, wv+4, ... keeping its own online-softmax partial; partials merged
// through LDS at the end.
__global__ __launch_bounds__(256) void attn_kernel(const unsigned short* __restrict__ q_ws,
                                                   const unsigned short* __restrict__ k_ws,
                                                   const unsigned short* __restrict__ vT,
                                                   float* __restrict__ out) {
  __shared__ float o_sm[4][16][65];   // [wave][q][h] padded
  __shared__ float lm_sm[4][16][2];   // [wave][q][{m,l}]

  const int wv = threadIdx.x >> 6, lane = threadIdx.x & 63;
  const int g = lane >> 4, nn = lane & 15;

  const int bid = blockIdx.x;             // 0..2047
  const int b = bid & 7;
  const int idx0 = bid >> 3;              // 0..255
  const int hf = idx0 >> 1;
  const int ti = (idx0 & 1) ? (255 - hf) : hf;   // long/short interleave
  const int t0 = ti * 16;
  const int tg = t0 + nn;                 // this lane's q row

  const unsigned short* qb = q_ws + ((size_t)(b * TS + tg)) * HS;
  const s16x8 qf0 = *(const s16x8*)(qb + 8 * g);
  const s16x8 qf1 = *(const s16x8*)(qb + 32 + 8 * g);

  const unsigned short* kptr = k_ws + (size_t)b * TS * HS;
  const unsigned short* vptr = vT + (size_t)b * HS * TS;

  f32x4 o[4];
#pragma unroll
  for (int i = 0; i < 4; ++i) o[i] = f32x4{0.f, 0.f, 0.f, 0.f};
  float m_run = -1e30f, l_run = 0.f;

  const int nt = (t0 + 47) >> 5;          // ceil((t0+16)/32)
  for (int it = wv; it < nt; it += 4) {
    const int s0 = it * 32;
    const unsigned short* k0 = kptr + (size_t)(s0 + nn) * HS;
    const unsigned short* k1 = kptr + (size_t)(s0 + 16 + nn) * HS;
    s16x8 ka0 = *(const s16x8*)(k0 + 8 * g);
    s16x8 ka1 = *(const s16x8*)(k0 + 32 + 8 * g);
    s16x8 kb0 = *(const s16x8*)(k1 + 8 * g);
    s16x8 kb1 = *(const s16x8*)(k1 + 32 + 8 * g);
    f32x4 st0 = f32x4{0.f, 0.f, 0.f, 0.f};
    f32x4 st1 = f32x4{0.f, 0.f, 0.f, 0.f};
    st0 = __builtin_amdgcn_mfma_f32_16x16x32_bf16(ka0, qf0, st0, 0, 0, 0);
    st0 = __builtin_amdgcn_mfma_f32_16x16x32_bf16(ka1, qf1, st0, 0, 0, 0);
    st1 = __builtin_amdgcn_mfma_f32_16x16x32_bf16(kb0, qf0, st1, 0, 0, 0);
    st1 = __builtin_amdgcn_mfma_f32_16x16x32_bf16(kb1, qf1, st1, 0, 0, 0);

    // causal mask: s = s0 + {0,16} + 4g + j vs q row tg
    const int sb0 = s0 + 4 * g, sb1 = s0 + 16 + 4 * g;
#pragma unroll
    for (int j = 0; j < 4; ++j) {
      if (sb0 + j > tg) st0[j] = -1e30f;
      if (sb1 + j > tg) st1[j] = -1e30f;
    }

    // online softmax (row q = nn; reduce across g via lane^16, lane^32)
    float mx = fmaxf(fmaxf(fmaxf(st0[0], st0[1]), fmaxf(st0[2], st0[3])),
                     fmaxf(fmaxf(st1[0], st1[1]), fmaxf(st1[2], st1[3])));
    mx = fmaxf(mx, __shfl_xor(mx, 16, 64));
    mx = fmaxf(mx, __shfl_xor(mx, 32, 64));
    const float m_new = fmaxf(m_run, mx);
    const float f = __builtin_amdgcn_exp2f(m_run - m_new);
    float p0[4], p1[4], sm = 0.f;
#pragma unroll
    for (int j = 0; j < 4; ++j) { p0[j] = __builtin_amdgcn_exp2f(st0[j] - m_new); sm += p0[j]; }
#pragma unroll
    for (int j = 0; j < 4; ++j) { p1[j] = __builtin_amdgcn_exp2f(st1[j] - m_new); sm += p1[j]; }
    sm += __shfl_xor(sm, 16, 64);
    sm += __shfl_xor(sm, 32, 64);
    l_run = l_run * f + sm;
    m_run = m_new;
#pragma unroll
    for (int i = 0; i < 4; ++i)
#pragma unroll
      for (int j = 0; j < 4; ++j) o[i][j] *= f;

    // relayout P -> P^T B-frag (lane needs s = 8g..8g+7 at col nn)
    const unsigned d00 = pkbf(p0[0], p0[1]), d01 = pkbf(p0[2], p0[3]);
    const unsigned d10 = pkbf(p1[0], p1[1]), d11 = pkbf(p1[2], p1[3]);
    const int laneA = nn | (((2 * g) & 3) << 4);
    const int laneB = nn | (((2 * g + 1) & 3) << 4);
    const unsigned eA0t0 = (unsigned)__shfl((int)d00, laneA, 64);
    const unsigned eA0t1 = (unsigned)__shfl((int)d10, laneA, 64);
    const unsigned eA1t0 = (unsigned)__shfl((int)d01, laneA, 64);
    const unsigned eA1t1 = (unsigned)__shfl((int)d11, laneA, 64);
    const unsigned eB0t0 = (unsigned)__shfl((int)d00, laneB, 64);
    const unsigned eB0t1 = (unsigned)__shfl((int)d10, laneB, 64);
    const unsigned eB1t0 = (unsigned)__shfl((int)d01, laneB, 64);
    const unsigned eB1t1 = (unsigned)__shfl((int)d11, laneB, 64);
    const bool hi = (g >= 2);
    ABFrag pb;
    pb.d[0] = hi ? eA0t1 : eA0t0;
    pb.d[1] = hi ? eA1t1 : eA1t0;
    pb.d[2] = hi ? eB0t1 : eB0t0;
    pb.d[3] = hi ? eB1t1 : eB1t0;

    // PV (swapped): O^T += V^T-frag * P^T-frag, 4 h-tiles
#pragma unroll
    for (int i = 0; i < 4; ++i) {
      s16x8 vf = *(const s16x8*)(vptr + (size_t)(16 * i + nn) * TS + s0 + 8 * g);
      o[i] = __builtin_amdgcn_mfma_f32_16x16x32_bf16(vf, pb.v, o[i], 0, 0, 0);
    }
  }

  // ---- write partials to LDS ----
#pragma unroll
  for (int i = 0; i < 4; ++i)
#pragma unroll
    for (int j = 0; j < 4; ++j)
      o_sm[wv][nn][16 * i + 4 * g + j] = o[i][j];
  if (lane < 16) { lm_sm[wv][lane][0] = m_run; lm_sm[wv][lane][1] = l_run; }
  __syncthreads();

  // ---- combine 4 partials; each thread owns 4 consecutive h of one q-row ----
  const int fidx = threadIdx.x * 4;       // 0..1023
  const int q = fidx >> 6, h0 = fidx & 63;
  const float m0v = lm_sm[0][q][0], m1v = lm_sm[1][q][0];
  const float m2v = lm_sm[2][q][0], m3v = lm_sm[3][q][0];
  const float M = fmaxf(fmaxf(m0v, m1v), fmaxf(m2v, m3v));
  const float w0 = __builtin_amdgcn_exp2f(m0v - M);
  const float w1 = __builtin_amdgcn_exp2f(m1v - M);
  const float w2 = __builtin_amdgcn_exp2f(m2v - M);
  const float w3 = __builtin_amdgcn_exp2f(m3v - M);
  const float L = w0 * lm_sm[0][q][1] + w1 * lm_sm[1][q][1] +
                  w2 * lm_sm[2][q][1] + w3 * lm_sm[3][q][1];
  const float inv = 1.0f / L;
  float4 r;
  float* rp = (float*)&r;
#pragma unroll
  for (int j = 0; j < 4; ++j) {
    rp[j] = (w0 * o_sm[0][q][h0 + j] + w1 * o_sm[1][q][h0 + j] +
             w2 * o_sm[2][q][h0 + j] + w3 * o_sm[3][q][h0 + j]) * inv;
  }
  *(float4*)(out + ((size_t)(b * TS + t0 + q)) * HS + h0) = r;
}

extern "C" void kernel_launch(void* const* d_in, const int* in_sizes, int n_in,
                              void* d_out, int out_size, void* d_ws, size_t ws_size,
                              hipStream_t stream) {
  const float* x  = (const float*)d_in[0];
  const float* Wk = (const float*)d_in[1];
  const float* Wq = (const float*)d_in[2];
  const float* Wv = (const float*)d_in[3];
  float* out = (float*)d_out;

  unsigned short* wT   = (unsigned short*)d_ws;
  unsigned short* q_ws = wT + 192 * 1024;
  unsigned short* k_ws = q_ws + (size_t)NROW * HS;
  unsigned short* vT   = k_ws + (size_t)NROW * HS;

  wt_kernel<<<dim3(768), dim3(256), 0, stream>>>(Wk, Wq, Wv, wT);
  qkv_kernel<<<dim3(NROW / 128), dim3(256), 0, stream>>>(x, wT, q_ws, k_ws, vT);
  attn_kernel<<<dim3(2048), dim3(256), 0, stream>>>(q_ws, k_ws, vT, out);
}

// Round 4
// 231.822 us; speedup vs baseline: 1.4408x; 1.3145x over previous
//
#include <hip/hip_runtime.h>
#include <hip/hip_bf16.h>

// Head: k/q/v projection + causal softmax attention, single head.
// B=8, T=4096, C=1024, H=64. All inputs fp32; output fp32.
//   k0: wT[n][k] bf16 transpose of [Wq|Wk|Wv]  (q cols pre-scaled by 0.125*log2e)
//   k1: qkv projection, 16 rows/wave, 2048 waves, native bf16 cvt, reg prefetch
//   k2: flash attention; block = 4 waves owns the PAIR (ti, 255-ti) of one
//       batch -> uniform work per block (ntA+ntB ~ 129 for all); 4-way strided
//       KV split per tile inside the block, LDS merge. 1024 blocks = 4/CU.

#define HS 64
#define NE 1024
#define NB 8
#define TS 4096
#define NROW (NB * TS)  // 32768

typedef __attribute__((ext_vector_type(4))) float  f32x4;
typedef __attribute__((ext_vector_type(8))) short  s16x8;  // bf16x8 MFMA fragment
typedef __attribute__((ext_vector_type(4))) float  vfloat4;

__device__ __forceinline__ unsigned short f2bf(float x) {
  return __builtin_bit_cast(unsigned short, __float2bfloat16(x));
}
__device__ __forceinline__ unsigned pkbf(float lo, float hi) {
  return (unsigned)f2bf(lo) | ((unsigned)f2bf(hi) << 16);
}

union ABFrag { s16x8 v; unsigned d[4]; };

// ---------------- kernel 0: weight transpose+cast ----------------
__global__ __launch_bounds__(256) void wt_kernel(const float* __restrict__ Wk,
                                                 const float* __restrict__ Wq,
                                                 const float* __restrict__ Wv,
                                                 unsigned short* __restrict__ wT) {
  int gid = blockIdx.x * 256 + threadIdx.x;   // 0..196607
  int n = gid >> 10, k = gid & 1023;
  const float* W = (n < 64) ? Wq : (n < 128) ? Wk : Wv;
  float s = (n < 64) ? 0.18033688011112042f : 1.0f;  // 0.125 * log2(e)
  wT[gid] = f2bf(W[k * 64 + (n & 63)] * s);
}

// ---------------- kernel 1: fused QKV projection ----------------
// 16 rows/wave, 4 waves/block -> 512 blocks (2/CU, 8 waves/CU).
// Per 32-K chunk: 12 MFMA; x and B-frags register-prefetched.
__global__ __launch_bounds__(256, 2) void qkv_kernel(const float* __restrict__ x,
                                                     const unsigned short* __restrict__ wT,
                                                     unsigned short* __restrict__ q_ws,
                                                     unsigned short* __restrict__ k_ws,
                                                     unsigned short* __restrict__ vT) {
  const int wv = threadIdx.x >> 6, lane = threadIdx.x & 63;
  const int g = lane >> 4, nn = lane & 15;
  const int m0 = blockIdx.x * 64 + wv * 16;

  f32x4 acc[12];
#pragma unroll
  for (int i = 0; i < 12; ++i) acc[i] = f32x4{0.f, 0.f, 0.f, 0.f};

  const float* xr = x + (size_t)(m0 + nn) * NE + 8 * g;
  const unsigned short* wp = wT + (size_t)nn * NE + 8 * g;

  vfloat4 xa = ((const vfloat4*)xr)[0];
  vfloat4 xb = ((const vfloat4*)xr)[1];
  s16x8 bc[12];
#pragma unroll
  for (int i = 0; i < 12; ++i) bc[i] = *(const s16x8*)(wp + (size_t)i * 16 * NE);

  for (int kc = 0; kc < NE; kc += 32) {
    ABFrag af;
    af.d[0] = pkbf(xa.x, xa.y); af.d[1] = pkbf(xa.z, xa.w);
    af.d[2] = pkbf(xb.x, xb.y); af.d[3] = pkbf(xb.z, xb.w);
    const bool more = (kc + 32 < NE);
    if (more) {
      xa = ((const vfloat4*)(xr + kc + 32))[0];
      xb = ((const vfloat4*)(xr + kc + 32))[1];
    }
#pragma unroll
    for (int i = 0; i < 12; ++i) {
      acc[i] = __builtin_amdgcn_mfma_f32_16x16x32_bf16(af.v, bc[i], acc[i], 0, 0, 0);
      if (more) bc[i] = *(const s16x8*)(wp + kc + 32 + (size_t)i * 16 * NE);
    }
  }

  // epilogue: D row = m0 + 4g + j, col = 16i + nn
  const int rbase = m0 + 4 * g;
#pragma unroll
  for (int i = 0; i < 12; ++i) {
    const int c = 16 * i + nn;
#pragma unroll
    for (int j = 0; j < 4; ++j) {
      const int rr = rbase + j;
      const unsigned short h = f2bf(acc[i][j]);
      if (c < 64) {
        q_ws[(size_t)rr * HS + c] = h;
      } else if (c < 128) {
        k_ws[(size_t)rr * HS + (c - 64)] = h;
      } else {
        const int b = rr >> 12, t = rr & 4095;
        vT[((size_t)(b * HS + (c - 128))) * TS + t] = h;
      }
    }
  }
}

// ---------------- kernel 2: causal flash attention, paired tiles ----------
// One KV tile (32 kv rows x 16 q rows) against running state (M,L,O).
#define TILE_ITER(S0, TG, QF0, QF1, M_RUN, L_RUN, O)                          \
  {                                                                           \
    const int s0_ = (S0);                                                     \
    const unsigned short* k0p = kptr + (size_t)(s0_ + nn) * HS + 8 * g;       \
    const unsigned short* k1p = kptr + (size_t)(s0_ + 16 + nn) * HS + 8 * g;  \
    s16x8 ka0 = *(const s16x8*)(k0p);                                         \
    s16x8 ka1 = *(const s16x8*)(k0p + 32);                                    \
    s16x8 kb0 = *(const s16x8*)(k1p);                                         \
    s16x8 kb1 = *(const s16x8*)(k1p + 32);                                    \
    f32x4 st0 = f32x4{0.f, 0.f, 0.f, 0.f};                                    \
    f32x4 st1 = f32x4{0.f, 0.f, 0.f, 0.f};                                    \
    st0 = __builtin_amdgcn_mfma_f32_16x16x32_bf16(ka0, QF0, st0, 0, 0, 0);    \
    st0 = __builtin_amdgcn_mfma_f32_16x16x32_bf16(ka1, QF1, st0, 0, 0, 0);    \
    st1 = __builtin_amdgcn_mfma_f32_16x16x32_bf16(kb0, QF0, st1, 0, 0, 0);    \
    st1 = __builtin_amdgcn_mfma_f32_16x16x32_bf16(kb1, QF1, st1, 0, 0, 0);    \
    const int sb0 = s0_ + 4 * g, sb1 = s0_ + 16 + 4 * g;                      \
    _Pragma("unroll")                                                         \
    for (int j = 0; j < 4; ++j) {                                             \
      if (sb0 + j > (TG)) st0[j] = -1e30f;                                    \
      if (sb1 + j > (TG)) st1[j] = -1e30f;                                    \
    }                                                                         \
    float mx = fmaxf(fmaxf(fmaxf(st0[0], st0[1]), fmaxf(st0[2], st0[3])),     \
                     fmaxf(fmaxf(st1[0], st1[1]), fmaxf(st1[2], st1[3])));    \
    mx = fmaxf(mx, __shfl_xor(mx, 16, 64));                                   \
    mx = fmaxf(mx, __shfl_xor(mx, 32, 64));                                   \
    const float m_new = fmaxf(M_RUN, mx);                                     \
    const float fsc = __builtin_amdgcn_exp2f(M_RUN - m_new);                  \
    float p0[4], p1[4], sm = 0.f;                                             \
    _Pragma("unroll")                                                         \
    for (int j = 0; j < 4; ++j) {                                             \
      p0[j] = __builtin_amdgcn_exp2f(st0[j] - m_new); sm += p0[j];            \
    }                                                                         \
    _Pragma("unroll")                                                         \
    for (int j = 0; j < 4; ++j) {                                             \
      p1[j] = __builtin_amdgcn_exp2f(st1[j] - m_new); sm += p1[j];            \
    }                                                                         \
    sm += __shfl_xor(sm, 16, 64);                                             \
    sm += __shfl_xor(sm, 32, 64);                                             \
    L_RUN = L_RUN * fsc + sm;                                                 \
    M_RUN = m_new;                                                            \
    _Pragma("unroll")                                                         \
    for (int i = 0; i < 4; ++i)                                               \
      _Pragma("unroll")                                                       \
      for (int j = 0; j < 4; ++j) O[i][j] *= fsc;                             \
    const unsigned d00 = pkbf(p0[0], p0[1]), d01 = pkbf(p0[2], p0[3]);        \
    const unsigned d10 = pkbf(p1[0], p1[1]), d11 = pkbf(p1[2], p1[3]);        \
    const int laneA = nn | (((2 * g) & 3) << 4);                              \
    const int laneB = nn | (((2 * g + 1) & 3) << 4);                          \
    const unsigned eA0t0 = (unsigned)__shfl((int)d00, laneA, 64);             \
    const unsigned eA0t1 = (unsigned)__shfl((int)d10, laneA, 64);             \
    const unsigned eA1t0 = (unsigned)__shfl((int)d01, laneA, 64);             \
    const unsigned eA1t1 = (unsigned)__shfl((int)d11, laneA, 64);             \
    const unsigned eB0t0 = (unsigned)__shfl((int)d00, laneB, 64);             \
    const unsigned eB0t1 = (unsigned)__shfl((int)d10, laneB, 64);             \
    const unsigned eB1t0 = (unsigned)__shfl((int)d01, laneB, 64);             \
    const unsigned eB1t1 = (unsigned)__shfl((int)d11, laneB, 64);             \
    const bool hi = (g >= 2);                                                 \
    ABFrag pb;                                                                \
    pb.d[0] = hi ? eA0t1 : eA0t0;                                             \
    pb.d[1] = hi ? eA1t1 : eA1t0;                                             \
    pb.d[2] = hi ? eB0t1 : eB0t0;                                             \
    pb.d[3] = hi ? eB1t1 : eB1t0;                                             \
    _Pragma("unroll")                                                         \
    for (int i = 0; i < 4; ++i) {                                             \
      s16x8 vf = *(const s16x8*)(vptr + (size_t)(16 * i + nn) * TS + s0_ + 8 * g); \
      O[i] = __builtin_amdgcn_mfma_f32_16x16x32_bf16(vf, pb.v, O[i], 0, 0, 0); \
    }                                                                         \
  }

__global__ __launch_bounds__(256, 4) void attn_kernel(const unsigned short* __restrict__ q_ws,
                                                      const unsigned short* __restrict__ k_ws,
                                                      const unsigned short* __restrict__ vT,
                                                      float* __restrict__ out) {
  __shared__ float o_smA[4][16][65];
  __shared__ float o_smB[4][16][65];
  __shared__ float lm_smA[4][16][2];
  __shared__ float lm_smB[4][16][2];

  const int wv = threadIdx.x >> 6, lane = threadIdx.x & 63;
  const int g = lane >> 4, nn = lane & 15;

  const int bid = blockIdx.x;             // 0..1023
  const int b = bid & 7;                  // batch <-> XCD alignment
  const int hf = bid >> 3;                // 0..127
  const int tA0 = hf * 16;
  const int tB0 = (255 - hf) * 16;
  const int tgA = tA0 + nn;
  const int tgB = tB0 + nn;

  const unsigned short* qbA = q_ws + ((size_t)(b * TS + tgA)) * HS;
  const unsigned short* qbB = q_ws + ((size_t)(b * TS + tgB)) * HS;
  const s16x8 qfA0 = *(const s16x8*)(qbA + 8 * g);
  const s16x8 qfA1 = *(const s16x8*)(qbA + 32 + 8 * g);
  const s16x8 qfB0 = *(const s16x8*)(qbB + 8 * g);
  const s16x8 qfB1 = *(const s16x8*)(qbB + 32 + 8 * g);

  const unsigned short* kptr = k_ws + (size_t)b * TS * HS;
  const unsigned short* vptr = vT + (size_t)b * HS * TS;

  f32x4 oA[4], oB[4];
#pragma unroll
  for (int i = 0; i < 4; ++i) { oA[i] = f32x4{0.f, 0.f, 0.f, 0.f}; oB[i] = f32x4{0.f, 0.f, 0.f, 0.f}; }
  float mA = -1e30f, lA = 0.f, mB = -1e30f, lB = 0.f;

  const int ntA = (tA0 + 47) >> 5;        // 1..64
  const int ntB = (tB0 + 47) >> 5;        // 65..128, always >= ntA
  for (int it = wv; it < ntB; it += 4) {
    if (it < ntA) TILE_ITER(it * 32, tgA, qfA0, qfA1, mA, lA, oA)
    TILE_ITER(it * 32, tgB, qfB0, qfB1, mB, lB, oB)
  }

  // ---- write partials to LDS ----
#pragma unroll
  for (int i = 0; i < 4; ++i)
#pragma unroll
    for (int j = 0; j < 4; ++j) {
      o_smA[wv][nn][16 * i + 4 * g + j] = oA[i][j];
      o_smB[wv][nn][16 * i + 4 * g + j] = oB[i][j];
    }
  if (lane < 16) {
    lm_smA[wv][lane][0] = mA; lm_smA[wv][lane][1] = lA;
    lm_smB[wv][lane][0] = mB; lm_smB[wv][lane][1] = lB;
  }
  __syncthreads();

  // ---- combine 4 partials per tile; thread owns 4 h of one q-row ----
  const int q = threadIdx.x >> 4, h0 = (threadIdx.x & 15) * 4;
  {
    const float m0v = lm_smA[0][q][0], m1v = lm_smA[1][q][0];
    const float m2v = lm_smA[2][q][0], m3v = lm_smA[3][q][0];
    const float M = fmaxf(fmaxf(m0v, m1v), fmaxf(m2v, m3v));
    const float w0 = __builtin_amdgcn_exp2f(m0v - M);
    const float w1 = __builtin_amdgcn_exp2f(m1v - M);
    const float w2 = __builtin_amdgcn_exp2f(m2v - M);
    const float w3 = __builtin_amdgcn_exp2f(m3v - M);
    const float L = w0 * lm_smA[0][q][1] + w1 * lm_smA[1][q][1] +
                    w2 * lm_smA[2][q][1] + w3 * lm_smA[3][q][1];
    const float inv = 1.0f / L;
    float4 r;
    float* rp = (float*)&r;
#pragma unroll
    for (int j = 0; j < 4; ++j)
      rp[j] = (w0 * o_smA[0][q][h0 + j] + w1 * o_smA[1][q][h0 + j] +
               w2 * o_smA[2][q][h0 + j] + w3 * o_smA[3][q][h0 + j]) * inv;
    *(float4*)(out + ((size_t)(b * TS + tA0 + q)) * HS + h0) = r;
  }
  {
    const float m0v = lm_smB[0][q][0], m1v = lm_smB[1][q][0];
    const float m2v = lm_smB[2][q][0], m3v = lm_smB[3][q][0];
    const float M = fmaxf(fmaxf(m0v, m1v), fmaxf(m2v, m3v));
    const float w0 = __builtin_amdgcn_exp2f(m0v - M);
    const float w1 = __builtin_amdgcn_exp2f(m1v - M);
    const float w2 = __builtin_amdgcn_exp2f(m2v - M);
    const float w3 = __builtin_amdgcn_exp2f(m3v - M);
    const float L = w0 * lm_smB[0][q][1] + w1 * lm_smB[1][q][1] +
                    w2 * lm_smB[2][q][1] + w3 * lm_smB[3][q][1];
    const float inv = 1.0f / L;
    float4 r;
    float* rp = (float*)&r;
#pragma unroll
    for (int j = 0; j < 4; ++j)
      rp[j] = (w0 * o_smB[0][q][h0 + j] + w1 * o_smB[1][q][h0 + j] +
               w2 * o_smB[2][q][h0 + j] + w3 * o_smB[3][q][h0 + j]) * inv;
    *(float4*)(out + ((size_t)(b * TS + tB0 + q)) * HS + h0) = r;
  }
}

extern "C" void kernel_launch(void* const* d_in, const int* in_sizes, int n_in,
                              void* d_out, int out_size, void* d_ws, size_t ws_size,
                              hipStream_t stream) {
  const float* x  = (const float*)d_in[0];
  const float* Wk = (const float*)d_in[1];
  const float* Wq = (const float*)d_in[2];
  const float* Wv = (const float*)d_in[3];
  float* out = (float*)d_out;

  unsigned short* wT   = (unsigned short*)d_ws;
  unsigned short* q_ws = wT + 192 * 1024;
  unsigned short* k_ws = q_ws + (size_t)NROW * HS;
  unsigned short* vT   = k_ws + (size_t)NROW * HS;

  wt_kernel<<<dim3(768), dim3(256), 0, stream>>>(Wk, Wq, Wv, wT);
  qkv_kernel<<<dim3(NROW / 64), dim3(256), 0, stream>>>(x, wT, q_ws, k_ws, vT);
  attn_kernel<<<dim3(1024), dim3(256), 0, stream>>>(q_ws, k_ws, vT, out);
}

// Round 8
// 175.395 us; speedup vs baseline: 1.9044x; 1.3217x over previous
//
#include <hip/hip_runtime.h>
#include <hip/hip_bf16.h>

// Head: k/q/v projection + causal softmax attention, single head.
// B=8, T=4096, C=1024, H=64. All inputs fp32; output fp32.
//   k0: wT[n][k] bf16 transpose of [Wq|Wk|Wv]  (q cols pre-scaled by 0.125*log2e)
//   k1: qkv projection (R4-verified version): 16 rows/wave, reg prefetch.
//   k2: flash attention, 32x32x16 MFMA swapped-operand form: softmax rows are
//       LANE-LOCAL (15 fmax); cross-half exchange via __shfl_xor(...,32)
//       (2 for reduces + 8 independent for P-relayout). Paired (ti,127-ti)
//       tiles per block, 4-way strided KV split, LDS merge. 512 blocks.
// R7 note: v_permlane32_swap_b32 removed entirely — two ~2.3-absmax failures
//   with both operand orders localize the bug to that instruction's assumed
//   half-swap semantics; shfl_xor(32) is the R2-R4-proven primitive.

#define HS 64
#define NE 1024
#define NB 8
#define TS 4096
#define NROW (NB * TS)  // 32768

typedef __attribute__((ext_vector_type(4)))  float f32x4;
typedef __attribute__((ext_vector_type(16))) float f32x16;
typedef __attribute__((ext_vector_type(8)))  short s16x8;   // bf16x8 MFMA fragment
typedef __attribute__((ext_vector_type(4)))  float vfloat4;

__device__ __forceinline__ unsigned short f2bf(float x) {
  return __builtin_bit_cast(unsigned short, __float2bfloat16(x));
}
__device__ __forceinline__ unsigned pkbf(float lo, float hi) {
  return (unsigned)f2bf(lo) | ((unsigned)f2bf(hi) << 16);
}

union ABFrag { s16x8 v; unsigned d[4]; };

// ---------------- kernel 0: weight transpose+cast ----------------
__global__ __launch_bounds__(256) void wt_kernel(const float* __restrict__ Wk,
                                                 const float* __restrict__ Wq,
                                                 const float* __restrict__ Wv,
                                                 unsigned short* __restrict__ wT) {
  int gid = blockIdx.x * 256 + threadIdx.x;   // 0..196607
  int n = gid >> 10, k = gid & 1023;
  const float* W = (n < 64) ? Wq : (n < 128) ? Wk : Wv;
  float s = (n < 64) ? 0.18033688011112042f : 1.0f;  // 0.125 * log2(e)
  wT[gid] = f2bf(W[k * 64 + (n & 63)] * s);
}

// ---------------- kernel 1: fused QKV projection (R4-verified) ----------
// 16 rows/wave, 4 waves/block -> 512 blocks. Per 32-K chunk: 12 MFMA;
// x and B-frags register-prefetched.
__global__ __launch_bounds__(256, 2) void qkv_kernel(const float* __restrict__ x,
                                                     const unsigned short* __restrict__ wT,
                                                     unsigned short* __restrict__ q_ws,
                                                     unsigned short* __restrict__ k_ws,
                                                     unsigned short* __restrict__ vT) {
  const int wv = threadIdx.x >> 6, lane = threadIdx.x & 63;
  const int g = lane >> 4, nn = lane & 15;
  const int m0 = blockIdx.x * 64 + wv * 16;

  f32x4 acc[12];
#pragma unroll
  for (int i = 0; i < 12; ++i) acc[i] = f32x4{0.f, 0.f, 0.f, 0.f};

  const float* xr = x + (size_t)(m0 + nn) * NE + 8 * g;
  const unsigned short* wp = wT + (size_t)nn * NE + 8 * g;

  vfloat4 xa = ((const vfloat4*)xr)[0];
  vfloat4 xb = ((const vfloat4*)xr)[1];
  s16x8 bc[12];
#pragma unroll
  for (int i = 0; i < 12; ++i) bc[i] = *(const s16x8*)(wp + (size_t)i * 16 * NE);

  for (int kc = 0; kc < NE; kc += 32) {
    ABFrag af;
    af.d[0] = pkbf(xa.x, xa.y); af.d[1] = pkbf(xa.z, xa.w);
    af.d[2] = pkbf(xb.x, xb.y); af.d[3] = pkbf(xb.z, xb.w);
    const bool more = (kc + 32 < NE);
    if (more) {
      xa = ((const vfloat4*)(xr + kc + 32))[0];
      xb = ((const vfloat4*)(xr + kc + 32))[1];
    }
#pragma unroll
    for (int i = 0; i < 12; ++i) {
      acc[i] = __builtin_amdgcn_mfma_f32_16x16x32_bf16(af.v, bc[i], acc[i], 0, 0, 0);
      if (more) bc[i] = *(const s16x8*)(wp + kc + 32 + (size_t)i * 16 * NE);
    }
  }

  // epilogue: D row = m0 + 4g + j, col = 16i + nn
  const int rbase = m0 + 4 * g;
#pragma unroll
  for (int i = 0; i < 12; ++i) {
    const int c = 16 * i + nn;
#pragma unroll
    for (int j = 0; j < 4; ++j) {
      const int rr = rbase + j;
      const unsigned short h = f2bf(acc[i][j]);
      if (c < 64) {
        q_ws[(size_t)rr * HS + c] = h;
      } else if (c < 128) {
        k_ws[(size_t)rr * HS + (c - 64)] = h;
      } else {
        const int b = rr >> 12, t = rr & 4095;
        vT[((size_t)(b * HS + (c - 128))) * TS + t] = h;
      }
    }
  }
}

// ---------------- kernel 2: causal flash attention, 32x32 lane-local -------
// S^T(32kv x 32q) = sum_kk mfma32x32x16(K-frag, Q^T-frag). Lane (qi,hi) holds
// st_[r] = S^T[kv=(r&3)+8*(r>>2)+4hi][q=qi]; the other 16 kv live in lane^32.
// Reduces and P^T B-frag assembly use __shfl_xor(...,32).
#define TILE32(S0, DIAG, QF, M_RUN, L_RUN, O)                                  \
  {                                                                            \
    const int s0_ = (S0);                                                      \
    const unsigned short* kr_ = kptr + (size_t)(s0_ + qi) * HS + hi8;          \
    const s16x8 ka0_ = *(const s16x8*)(kr_);                                   \
    const s16x8 ka1_ = *(const s16x8*)(kr_ + 16);                              \
    const s16x8 ka2_ = *(const s16x8*)(kr_ + 32);                              \
    const s16x8 ka3_ = *(const s16x8*)(kr_ + 48);                              \
    const unsigned short* vr0_ = vptr + (size_t)qi * TS + s0_ + hi8;           \
    const unsigned short* vr1_ = vptr + (size_t)(32 + qi) * TS + s0_ + hi8;    \
    f32x16 st_;                                                                \
    _Pragma("unroll") for (int r = 0; r < 16; ++r) st_[r] = 0.f;               \
    st_ = __builtin_amdgcn_mfma_f32_32x32x16_bf16(ka0_, QF[0], st_, 0, 0, 0);  \
    st_ = __builtin_amdgcn_mfma_f32_32x32x16_bf16(ka1_, QF[1], st_, 0, 0, 0);  \
    st_ = __builtin_amdgcn_mfma_f32_32x32x16_bf16(ka2_, QF[2], st_, 0, 0, 0);  \
    st_ = __builtin_amdgcn_mfma_f32_32x32x16_bf16(ka3_, QF[3], st_, 0, 0, 0);  \
    if (DIAG) {                                                                \
      _Pragma("unroll") for (int r = 0; r < 16; ++r) {                         \
        const int kvl_ = (r & 3) + 8 * (r >> 2) + hi4;                         \
        if (kvl_ > qi) st_[r] = -1e30f;                                        \
      }                                                                        \
    }                                                                          \
    float mx_ =                                                                \
      fmaxf(fmaxf(fmaxf(fmaxf(st_[0], st_[1]), fmaxf(st_[2], st_[3])),         \
                  fmaxf(fmaxf(st_[4], st_[5]), fmaxf(st_[6], st_[7]))),        \
            fmaxf(fmaxf(fmaxf(st_[8], st_[9]), fmaxf(st_[10], st_[11])),       \
                  fmaxf(fmaxf(st_[12], st_[13]), fmaxf(st_[14], st_[15]))));   \
    mx_ = fmaxf(mx_, __shfl_xor(mx_, 32, 64));                                 \
    const float mn_ = fmaxf(M_RUN, mx_);                                       \
    if (__ballot(mn_ > M_RUN)) {                                               \
      const float fs_ = __builtin_amdgcn_exp2f(M_RUN - mn_);                   \
      _Pragma("unroll") for (int r = 0; r < 16; ++r) {                         \
        O[0][r] *= fs_; O[1][r] *= fs_;                                        \
      }                                                                        \
      L_RUN *= fs_;                                                            \
      M_RUN = mn_;                                                             \
    }                                                                          \
    float p_[16];                                                              \
    _Pragma("unroll") for (int r = 0; r < 16; ++r)                             \
      p_[r] = __builtin_amdgcn_exp2f(st_[r] - M_RUN);                          \
    float sm_ = ((p_[0] + p_[1]) + (p_[2] + p_[3])) +                          \
                ((p_[4] + p_[5]) + (p_[6] + p_[7]));                           \
    sm_ += ((p_[8] + p_[9]) + (p_[10] + p_[11])) +                             \
           ((p_[12] + p_[13]) + (p_[14] + p_[15]));                            \
    sm_ += __shfl_xor(sm_, 32, 64);                                            \
    L_RUN += sm_;                                                              \
    const unsigned q01_ = pkbf(p_[0], p_[1]),   q23_ = pkbf(p_[2], p_[3]);     \
    const unsigned q45_ = pkbf(p_[4], p_[5]),   q67_ = pkbf(p_[6], p_[7]);     \
    const unsigned q89_ = pkbf(p_[8], p_[9]),   qab_ = pkbf(p_[10], p_[11]);   \
    const unsigned qcd_ = pkbf(p_[12], p_[13]), qef_ = pkbf(p_[14], p_[15]);   \
    const unsigned t01_ = (unsigned)__shfl_xor((int)q01_, 32, 64);             \
    const unsigned t23_ = (unsigned)__shfl_xor((int)q23_, 32, 64);             \
    const unsigned t45_ = (unsigned)__shfl_xor((int)q45_, 32, 64);             \
    const unsigned t67_ = (unsigned)__shfl_xor((int)q67_, 32, 64);             \
    const unsigned t89_ = (unsigned)__shfl_xor((int)q89_, 32, 64);             \
    const unsigned tab_ = (unsigned)__shfl_xor((int)qab_, 32, 64);             \
    const unsigned tcd_ = (unsigned)__shfl_xor((int)qcd_, 32, 64);             \
    const unsigned tef_ = (unsigned)__shfl_xor((int)qef_, 32, 64);             \
    ABFrag pf0_, pf1_;                                                         \
    pf0_.d[0] = hi ? t45_ : q01_;                                              \
    pf0_.d[1] = hi ? t67_ : q23_;                                              \
    pf0_.d[2] = hi ? q45_ : t01_;                                              \
    pf0_.d[3] = hi ? q67_ : t23_;                                              \
    pf1_.d[0] = hi ? tcd_ : q89_;                                              \
    pf1_.d[1] = hi ? tef_ : qab_;                                              \
    pf1_.d[2] = hi ? qcd_ : t89_;                                              \
    pf1_.d[3] = hi ? qef_ : tab_;                                              \
    const s16x8 vf00_ = *(const s16x8*)(vr0_);                                 \
    const s16x8 vf01_ = *(const s16x8*)(vr0_ + 16);                            \
    const s16x8 vf10_ = *(const s16x8*)(vr1_);                                 \
    const s16x8 vf11_ = *(const s16x8*)(vr1_ + 16);                            \
    O[0] = __builtin_amdgcn_mfma_f32_32x32x16_bf16(vf00_, pf0_.v, O[0], 0,0,0);\
    O[0] = __builtin_amdgcn_mfma_f32_32x32x16_bf16(vf01_, pf1_.v, O[0], 0,0,0);\
    O[1] = __builtin_amdgcn_mfma_f32_32x32x16_bf16(vf10_, pf0_.v, O[1], 0,0,0);\
    O[1] = __builtin_amdgcn_mfma_f32_32x32x16_bf16(vf11_, pf1_.v, O[1], 0,0,0);\
  }

__global__ __launch_bounds__(256, 2) void attn_kernel(const unsigned short* __restrict__ q_ws,
                                                      const unsigned short* __restrict__ k_ws,
                                                      const unsigned short* __restrict__ vT,
                                                      float* __restrict__ out) {
  __shared__ float o_sm[2][4][32][68];   // [tile][wave][q][h] padded
  __shared__ float lm_sm[2][4][32][2];

  const int wv = threadIdx.x >> 6, lane = threadIdx.x & 63;
  const int qi = lane & 31, hi = lane >> 5;
  const int hi8 = 8 * hi, hi4 = 4 * hi;

  const int bid = blockIdx.x;             // 0..511
  const int b = bid & 7;                  // batch <-> XCD alignment
  const int pr = bid >> 3;                // 0..63
  const int tiA = pr, tiB = 127 - pr;     // paired long/short 32-row tiles
  const int t0A = tiA * 32, t0B = tiB * 32;

  const unsigned short* kptr = k_ws + (size_t)b * TS * HS;
  const unsigned short* vptr = vT + (size_t)b * HS * TS;
  const unsigned short* qrA = q_ws + (size_t)(b * TS + t0A + qi) * HS + hi8;
  const unsigned short* qrB = q_ws + (size_t)(b * TS + t0B + qi) * HS + hi8;

  s16x8 qfA[4], qfB[4];
#pragma unroll
  for (int kk = 0; kk < 4; ++kk) {
    qfA[kk] = *(const s16x8*)(qrA + 16 * kk);
    qfB[kk] = *(const s16x8*)(qrB + 16 * kk);
  }

  f32x16 oA[2], oB[2];
#pragma unroll
  for (int r = 0; r < 16; ++r) { oA[0][r] = 0.f; oA[1][r] = 0.f; oB[0][r] = 0.f; oB[1][r] = 0.f; }
  float mA = -1e30f, lA = 0.f, mB = -1e30f, lB = 0.f;

  const int ntA = tiA + 1, ntB = tiB + 1;
  for (int it = wv; it < ntB; it += 4) {
    const int s0 = it * 32;
    if (it < ntA) TILE32(s0, it == tiA, qfA, mA, lA, oA)
    TILE32(s0, it == tiB, qfB, mB, lB, oB)
  }

  // ---- partials to LDS ----
#pragma unroll
  for (int ht = 0; ht < 2; ++ht)
#pragma unroll
    for (int r = 0; r < 16; ++r) {
      const int h = ht * 32 + (r & 3) + 8 * (r >> 2) + hi4;
      o_sm[0][wv][qi][h] = oA[ht][r];
      o_sm[1][wv][qi][h] = oB[ht][r];
    }
  if (lane < 32) {
    lm_sm[0][wv][lane][0] = mA; lm_sm[0][wv][lane][1] = lA;
    lm_sm[1][wv][lane][0] = mB; lm_sm[1][wv][lane][1] = lB;
  }
  __syncthreads();

  // ---- merge 4 partials per tile; thread owns (q, 8 h) ----
  const int q = threadIdx.x >> 3;         // 0..31
  const int h0 = (threadIdx.x & 7) * 8;   // 0..56
  const int t0X[2] = {t0A, t0B};
#pragma unroll
  for (int X = 0; X < 2; ++X) {
    const float m0v = lm_sm[X][0][q][0], m1v = lm_sm[X][1][q][0];
    const float m2v = lm_sm[X][2][q][0], m3v = lm_sm[X][3][q][0];
    const float M = fmaxf(fmaxf(m0v, m1v), fmaxf(m2v, m3v));
    const float w0 = __builtin_amdgcn_exp2f(m0v - M);
    const float w1 = __builtin_amdgcn_exp2f(m1v - M);
    const float w2 = __builtin_amdgcn_exp2f(m2v - M);
    const float w3 = __builtin_amdgcn_exp2f(m3v - M);
    const float L = w0 * lm_sm[X][0][q][1] + w1 * lm_sm[X][1][q][1] +
                    w2 * lm_sm[X][2][q][1] + w3 * lm_sm[X][3][q][1];
    const float inv = 1.0f / L;
    float rv[8];
#pragma unroll
    for (int j = 0; j < 8; ++j)
      rv[j] = (w0 * o_sm[X][0][q][h0 + j] + w1 * o_sm[X][1][q][h0 + j] +
               w2 * o_sm[X][2][q][h0 + j] + w3 * o_sm[X][3][q][h0 + j]) * inv;
    float* ob = out + ((size_t)(b * TS + t0X[X] + q)) * HS + h0;
    *(float4*)(ob)     = float4{rv[0], rv[1], rv[2], rv[3]};
    *(float4*)(ob + 4) = float4{rv[4], rv[5], rv[6], rv[7]};
  }
}

extern "C" void kernel_launch(void* const* d_in, const int* in_sizes, int n_in,
                              void* d_out, int out_size, void* d_ws, size_t ws_size,
                              hipStream_t stream) {
  const float* x  = (const float*)d_in[0];
  const float* Wk = (const float*)d_in[1];
  const float* Wq = (const float*)d_in[2];
  const float* Wv = (const float*)d_in[3];
  float* out = (float*)d_out;

  unsigned short* wT   = (unsigned short*)d_ws;
  unsigned short* q_ws = wT + 192 * 1024;
  unsigned short* k_ws = q_ws + (size_t)NROW * HS;
  unsigned short* vT   = k_ws + (size_t)NROW * HS;

  wt_kernel<<<dim3(768), dim3(256), 0, stream>>>(Wk, Wq, Wv, wT);
  qkv_kernel<<<dim3(NROW / 64), dim3(256), 0, stream>>>(x, wT, q_ws, k_ws, vT);
  attn_kernel<<<dim3(512), dim3(256), 0, stream>>>(q_ws, k_ws, vT, out);
}

// Round 9
// 120.569 us; speedup vs baseline: 2.7703x; 1.4547x over previous
//
#include <hip/hip_runtime.h>
#include <hip/hip_bf16.h>

// Head: k/q/v projection + causal softmax attention, single head.
// B=8, T=4096, C=1024, H=64. All inputs fp32; output fp32.
//   k0: wT[n][k] bf16 transpose of [Wq|Wk|Wv]  (q cols pre-scaled by 0.125*log2e)
//   k1: qkv projection v3: wT chunk staged in double-buffered LDS (reg-staged,
//       issue-early/write-late), raw-barrier 2-phase pipeline (no vmcnt(0) in
//       loop), x register-prefetch depth-2. R8's 123us was latency-stalled:
//       VGPR=68 proved bc[12] prefetch was rematerialized at use (200cyc L2
//       per MFMA). LDS ds_read_b128 ~12cyc fixes it.
//   k2: flash attention (R8-verified): 32x32x16 swapped-operand, lane-local
//       softmax, shfl_xor(32) exchanges, paired (ti,127-ti) tiles, 4-way KV
//       split, LDS merge.

#define HS 64
#define NE 1024
#define NB 8
#define TS 4096
#define NROW (NB * TS)  // 32768

typedef __attribute__((ext_vector_type(4)))  float f32x4;
typedef __attribute__((ext_vector_type(16))) float f32x16;
typedef __attribute__((ext_vector_type(8)))  short s16x8;   // bf16x8 MFMA fragment
typedef __attribute__((ext_vector_type(4)))  float vfloat4;

__device__ __forceinline__ unsigned short f2bf(float x) {
  return __builtin_bit_cast(unsigned short, __float2bfloat16(x));
}
__device__ __forceinline__ unsigned pkbf(float lo, float hi) {
  return (unsigned)f2bf(lo) | ((unsigned)f2bf(hi) << 16);
}

union ABFrag { s16x8 v; unsigned d[4]; };

// ---------------- kernel 0: weight transpose+cast ----------------
__global__ __launch_bounds__(256) void wt_kernel(const float* __restrict__ Wk,
                                                 const float* __restrict__ Wq,
                                                 const float* __restrict__ Wv,
                                                 unsigned short* __restrict__ wT) {
  int gid = blockIdx.x * 256 + threadIdx.x;   // 0..196607
  int n = gid >> 10, k = gid & 1023;
  const float* W = (n < 64) ? Wq : (n < 128) ? Wk : Wv;
  float s = (n < 64) ? 0.18033688011112042f : 1.0f;  // 0.125 * log2(e)
  wT[gid] = f2bf(W[k * 64 + (n & 63)] * s);
}

// ---------------- kernel 1: fused QKV projection v3 ----------------
// Block 256 thd = 4 waves, 64 rows (16/wave), all 192 cols. Per 32-K chunk:
// LDS buffer layout (bytes): g-block g in [0,4) at g*3088 (3072 data + 16 pad
// for bank stagger); entry row n at +n*16 holds wT[n][kc*32+8g..+7].
// Stage: wave wv = g-block wv, parts p=0..2: row 64p+lane.
// MFMA i reads gblk=g, row=16i+nn -> uniform 8 dwords/bank (b128 minimum).
__global__ __launch_bounds__(256, 2) void qkv_kernel(const float* __restrict__ x,
                                                     const unsigned short* __restrict__ wT,
                                                     unsigned short* __restrict__ q_ws,
                                                     unsigned short* __restrict__ k_ws,
                                                     unsigned short* __restrict__ vT) {
  __shared__ __align__(16) unsigned short wbuf[2][6176];  // 2 x 12352 B
  const int wv = threadIdx.x >> 6, lane = threadIdx.x & 63;
  const int g = lane >> 4, nn = lane & 15;
  const int m0 = blockIdx.x * 64 + wv * 16;

  f32x4 acc[12];
#pragma unroll
  for (int i = 0; i < 12; ++i) acc[i] = f32x4{0.f, 0.f, 0.f, 0.f};

  const float* xr = x + (size_t)(m0 + nn) * NE + 8 * g;
  // stage sources: row 64p+lane, k-sub wv
  const unsigned short* sp0 = wT + (size_t)lane * NE + wv * 8;
  const unsigned short* sp1 = wT + (size_t)(64 + lane) * NE + wv * 8;
  const unsigned short* sp2 = wT + (size_t)(128 + lane) * NE + wv * 8;
  const int wdofs = wv * 1544 + lane * 8;   // ushort units; +p*512

  // ---- prologue: stage chunk0 -> buf0; x chunks 0,1 -> regs ----
  s16x8 stg0 = *(const s16x8*)(sp0);
  s16x8 stg1 = *(const s16x8*)(sp1);
  s16x8 stg2 = *(const s16x8*)(sp2);
  vfloat4 x0a = ((const vfloat4*)(xr))[0],      x0b = ((const vfloat4*)(xr))[1];
  vfloat4 x1a = ((const vfloat4*)(xr + 32))[0], x1b = ((const vfloat4*)(xr + 32))[1];
  *(s16x8*)&wbuf[0][wdofs]        = stg0;
  *(s16x8*)&wbuf[0][wdofs + 512]  = stg1;
  *(s16x8*)&wbuf[0][wdofs + 1024] = stg2;
  asm volatile("s_waitcnt lgkmcnt(0)" ::: "memory");
  __builtin_amdgcn_s_barrier();
  __builtin_amdgcn_sched_barrier(0);
  stg0 = *(const s16x8*)(sp0 + 32);
  stg1 = *(const s16x8*)(sp1 + 32);
  stg2 = *(const s16x8*)(sp2 + 32);

  for (int kc2 = 0; kc2 < 16; ++kc2) {
    const int k = 2 * kc2;
    // ======== EVEN chunk k: compute from buf0 ========
    {
      ABFrag af;
      af.d[0] = pkbf(x0a.x, x0a.y); af.d[1] = pkbf(x0a.z, x0a.w);
      af.d[2] = pkbf(x0b.x, x0b.y); af.d[3] = pkbf(x0b.z, x0b.w);
      if (kc2 < 15) {  // issue x chunk k+2 into slot 0
        x0a = ((const vfloat4*)(xr + (k + 2) * 32))[0];
        x0b = ((const vfloat4*)(xr + (k + 2) * 32))[1];
      }
#pragma unroll
      for (int i = 0; i < 12; ++i) {
        const s16x8 bf = *(const s16x8*)&wbuf[0][g * 1544 + (16 * i + nn) * 8];
        acc[i] = __builtin_amdgcn_mfma_f32_16x16x32_bf16(af.v, bf, acc[i], 0, 0, 0);
      }
      // write stage (chunk k+1) -> buf1, then raw barrier (vmem stays in flight)
      *(s16x8*)&wbuf[1][wdofs]        = stg0;
      *(s16x8*)&wbuf[1][wdofs + 512]  = stg1;
      *(s16x8*)&wbuf[1][wdofs + 1024] = stg2;
      asm volatile("s_waitcnt lgkmcnt(0)" ::: "memory");
      __builtin_amdgcn_s_barrier();
      __builtin_amdgcn_sched_barrier(0);
      if (kc2 < 15) {  // issue stage chunk k+2
        stg0 = *(const s16x8*)(sp0 + (k + 2) * 32);
        stg1 = *(const s16x8*)(sp1 + (k + 2) * 32);
        stg2 = *(const s16x8*)(sp2 + (k + 2) * 32);
      }
    }
    // ======== ODD chunk k+1: compute from buf1 ========
    {
      ABFrag af;
      af.d[0] = pkbf(x1a.x, x1a.y); af.d[1] = pkbf(x1a.z, x1a.w);
      af.d[2] = pkbf(x1b.x, x1b.y); af.d[3] = pkbf(x1b.z, x1b.w);
      if (kc2 < 15) {  // issue x chunk k+3 into slot 1
        x1a = ((const vfloat4*)(xr + (k + 3) * 32))[0];
        x1b = ((const vfloat4*)(xr + (k + 3) * 32))[1];
      }
#pragma unroll
      for (int i = 0; i < 12; ++i) {
        const s16x8 bf = *(const s16x8*)&wbuf[1][g * 1544 + (16 * i + nn) * 8];
        acc[i] = __builtin_amdgcn_mfma_f32_16x16x32_bf16(af.v, bf, acc[i], 0, 0, 0);
      }
      if (kc2 < 15) {
        // write stage (chunk k+2) -> buf0 + barrier
        *(s16x8*)&wbuf[0][wdofs]        = stg0;
        *(s16x8*)&wbuf[0][wdofs + 512]  = stg1;
        *(s16x8*)&wbuf[0][wdofs + 1024] = stg2;
        asm volatile("s_waitcnt lgkmcnt(0)" ::: "memory");
        __builtin_amdgcn_s_barrier();
        __builtin_amdgcn_sched_barrier(0);
        // issue stage chunk k+3
        stg0 = *(const s16x8*)(sp0 + (k + 3) * 32);
        stg1 = *(const s16x8*)(sp1 + (k + 3) * 32);
        stg2 = *(const s16x8*)(sp2 + (k + 3) * 32);
      }
    }
  }

  // epilogue: D row = m0 + 4g + j, col = 16i + nn
  const int rbase = m0 + 4 * g;
#pragma unroll
  for (int i = 0; i < 12; ++i) {
    const int c = 16 * i + nn;
#pragma unroll
    for (int j = 0; j < 4; ++j) {
      const int rr = rbase + j;
      const unsigned short h = f2bf(acc[i][j]);
      if (c < 64) {
        q_ws[(size_t)rr * HS + c] = h;
      } else if (c < 128) {
        k_ws[(size_t)rr * HS + (c - 64)] = h;
      } else {
        const int b = rr >> 12, t = rr & 4095;
        vT[((size_t)(b * HS + (c - 128))) * TS + t] = h;
      }
    }
  }
}

// ---------------- kernel 2: causal flash attention, 32x32 lane-local -------
// S^T(32kv x 32q) = sum_kk mfma32x32x16(K-frag, Q^T-frag). Lane (qi,hi) holds
// st_[r] = S^T[kv=(r&3)+8*(r>>2)+4hi][q=qi]; the other 16 kv live in lane^32.
// Reduces and P^T B-frag assembly use __shfl_xor(...,32).
#define TILE32(S0, DIAG, QF, M_RUN, L_RUN, O)                                  \
  {                                                                            \
    const int s0_ = (S0);                                                      \
    const unsigned short* kr_ = kptr + (size_t)(s0_ + qi) * HS + hi8;          \
    const s16x8 ka0_ = *(const s16x8*)(kr_);                                   \
    const s16x8 ka1_ = *(const s16x8*)(kr_ + 16);                              \
    const s16x8 ka2_ = *(const s16x8*)(kr_ + 32);                              \
    const s16x8 ka3_ = *(const s16x8*)(kr_ + 48);                              \
    const unsigned short* vr0_ = vptr + (size_t)qi * TS + s0_ + hi8;           \
    const unsigned short* vr1_ = vptr + (size_t)(32 + qi) * TS + s0_ + hi8;    \
    f32x16 st_;                                                                \
    _Pragma("unroll") for (int r = 0; r < 16; ++r) st_[r] = 0.f;               \
    st_ = __builtin_amdgcn_mfma_f32_32x32x16_bf16(ka0_, QF[0], st_, 0, 0, 0);  \
    st_ = __builtin_amdgcn_mfma_f32_32x32x16_bf16(ka1_, QF[1], st_, 0, 0, 0);  \
    st_ = __builtin_amdgcn_mfma_f32_32x32x16_bf16(ka2_, QF[2], st_, 0, 0, 0);  \
    st_ = __builtin_amdgcn_mfma_f32_32x32x16_bf16(ka3_, QF[3], st_, 0, 0, 0);  \
    if (DIAG) {                                                                \
      _Pragma("unroll") for (int r = 0; r < 16; ++r) {                         \
        const int kvl_ = (r & 3) + 8 * (r >> 2) + hi4;                         \
        if (kvl_ > qi) st_[r] = -1e30f;                                        \
      }                                                                        \
    }                                                                          \
    float mx_ =                                                                \
      fmaxf(fmaxf(fmaxf(fmaxf(st_[0], st_[1]), fmaxf(st_[2], st_[3])),         \
                  fmaxf(fmaxf(st_[4], st_[5]), fmaxf(st_[6], st_[7]))),        \
            fmaxf(fmaxf(fmaxf(st_[8], st_[9]), fmaxf(st_[10], st_[11])),       \
                  fmaxf(fmaxf(st_[12], st_[13]), fmaxf(st_[14], st_[15]))));   \
    mx_ = fmaxf(mx_, __shfl_xor(mx_, 32, 64));                                 \
    const float mn_ = fmaxf(M_RUN, mx_);                                       \
    if (__ballot(mn_ > M_RUN)) {                                               \
      const float fs_ = __builtin_amdgcn_exp2f(M_RUN - mn_);                   \
      _Pragma("unroll") for (int r = 0; r < 16; ++r) {                         \
        O[0][r] *= fs_; O[1][r] *= fs_;                                        \
      }                                                                        \
      L_RUN *= fs_;                                                            \
      M_RUN = mn_;                                                             \
    }                                                                          \
    float p_[16];                                                              \
    _Pragma("unroll") for (int r = 0; r < 16; ++r)                             \
      p_[r] = __builtin_amdgcn_exp2f(st_[r] - M_RUN);                          \
    float sm_ = ((p_[0] + p_[1]) + (p_[2] + p_[3])) +                          \
                ((p_[4] + p_[5]) + (p_[6] + p_[7]));                           \
    sm_ += ((p_[8] + p_[9]) + (p_[10] + p_[11])) +                             \
           ((p_[12] + p_[13]) + (p_[14] + p_[15]));                            \
    sm_ += __shfl_xor(sm_, 32, 64);                                            \
    L_RUN += sm_;                                                              \
    const unsigned q01_ = pkbf(p_[0], p_[1]),   q23_ = pkbf(p_[2], p_[3]);     \
    const unsigned q45_ = pkbf(p_[4], p_[5]),   q67_ = pkbf(p_[6], p_[7]);     \
    const unsigned q89_ = pkbf(p_[8], p_[9]),   qab_ = pkbf(p_[10], p_[11]);   \
    const unsigned qcd_ = pkbf(p_[12], p_[13]), qef_ = pkbf(p_[14], p_[15]);   \
    const unsigned t01_ = (unsigned)__shfl_xor((int)q01_, 32, 64);             \
    const unsigned t23_ = (unsigned)__shfl_xor((int)q23_, 32, 64);             \
    const unsigned t45_ = (unsigned)__shfl_xor((int)q45_, 32, 64);             \
    const unsigned t67_ = (unsigned)__shfl_xor((int)q67_, 32, 64);             \
    const unsigned t89_ = (unsigned)__shfl_xor((int)q89_, 32, 64);             \
    const unsigned tab_ = (unsigned)__shfl_xor((int)qab_, 32, 64);             \
    const unsigned tcd_ = (unsigned)__shfl_xor((int)qcd_, 32, 64);             \
    const unsigned tef_ = (unsigned)__shfl_xor((int)qef_, 32, 64);             \
    ABFrag pf0_, pf1_;                                                         \
    pf0_.d[0] = hi ? t45_ : q01_;                                              \
    pf0_.d[1] = hi ? t67_ : q23_;                                              \
    pf0_.d[2] = hi ? q45_ : t01_;                                              \
    pf0_.d[3] = hi ? q67_ : t23_;                                              \
    pf1_.d[0] = hi ? tcd_ : q89_;                                              \
    pf1_.d[1] = hi ? tef_ : qab_;                                              \
    pf1_.d[2] = hi ? qcd_ : t89_;                                              \
    pf1_.d[3] = hi ? qef_ : tab_;                                              \
    const s16x8 vf00_ = *(const s16x8*)(vr0_);                                 \
    const s16x8 vf01_ = *(const s16x8*)(vr0_ + 16);                            \
    const s16x8 vf10_ = *(const s16x8*)(vr1_);                                 \
    const s16x8 vf11_ = *(const s16x8*)(vr1_ + 16);                            \
    O[0] = __builtin_amdgcn_mfma_f32_32x32x16_bf16(vf00_, pf0_.v, O[0], 0,0,0);\
    O[0] = __builtin_amdgcn_mfma_f32_32x32x16_bf16(vf01_, pf1_.v, O[0], 0,0,0);\
    O[1] = __builtin_amdgcn_mfma_f32_32x32x16_bf16(vf10_, pf0_.v, O[1], 0,0,0);\
    O[1] = __builtin_amdgcn_mfma_f32_32x32x16_bf16(vf11_, pf1_.v, O[1], 0,0,0);\
  }

__global__ __launch_bounds__(256, 2) void attn_kernel(const unsigned short* __restrict__ q_ws,
                                                      const unsigned short* __restrict__ k_ws,
                                                      const unsigned short* __restrict__ vT,
                                                      float* __restrict__ out) {
  __shared__ float o_sm[2][4][32][68];   // [tile][wave][q][h] padded
  __shared__ float lm_sm[2][4][32][2];

  const int wv = threadIdx.x >> 6, lane = threadIdx.x & 63;
  const int qi = lane & 31, hi = lane >> 5;
  const int hi8 = 8 * hi, hi4 = 4 * hi;

  const int bid = blockIdx.x;             // 0..511
  const int b = bid & 7;                  // batch <-> XCD alignment
  const int pr = bid >> 3;                // 0..63
  const int tiA = pr, tiB = 127 - pr;     // paired long/short 32-row tiles
  const int t0A = tiA * 32, t0B = tiB * 32;

  const unsigned short* kptr = k_ws + (size_t)b * TS * HS;
  const unsigned short* vptr = vT + (size_t)b * HS * TS;
  const unsigned short* qrA = q_ws + (size_t)(b * TS + t0A + qi) * HS + hi8;
  const unsigned short* qrB = q_ws + (size_t)(b * TS + t0B + qi) * HS + hi8;

  s16x8 qfA[4], qfB[4];
#pragma unroll
  for (int kk = 0; kk < 4; ++kk) {
    qfA[kk] = *(const s16x8*)(qrA + 16 * kk);
    qfB[kk] = *(const s16x8*)(qrB + 16 * kk);
  }

  f32x16 oA[2], oB[2];
#pragma unroll
  for (int r = 0; r < 16; ++r) { oA[0][r] = 0.f; oA[1][r] = 0.f; oB[0][r] = 0.f; oB[1][r] = 0.f; }
  float mA = -1e30f, lA = 0.f, mB = -1e30f, lB = 0.f;

  const int ntA = tiA + 1, ntB = tiB + 1;
  for (int it = wv; it < ntB; it += 4) {
    const int s0 = it * 32;
    if (it < ntA) TILE32(s0, it == tiA, qfA, mA, lA, oA)
    TILE32(s0, it == tiB, qfB, mB, lB, oB)
  }

  // ---- partials to LDS ----
#pragma unroll
  for (int ht = 0; ht < 2; ++ht)
#pragma unroll
    for (int r = 0; r < 16; ++r) {
      const int h = ht * 32 + (r & 3) + 8 * (r >> 2) + hi4;
      o_sm[0][wv][qi][h] = oA[ht][r];
      o_sm[1][wv][qi][h] = oB[ht][r];
    }
  if (lane < 32) {
    lm_sm[0][wv][lane][0] = mA; lm_sm[0][wv][lane][1] = lA;
    lm_sm[1][wv][lane][0] = mB; lm_sm[1][wv][lane][1] = lB;
  }
  __syncthreads();

  // ---- merge 4 partials per tile; thread owns (q, 8 h) ----
  const int q = threadIdx.x >> 3;         // 0..31
  const int h0 = (threadIdx.x & 7) * 8;   // 0..56
  const int t0X[2] = {t0A, t0B};
#pragma unroll
  for (int X = 0; X < 2; ++X) {
    const float m0v = lm_sm[X][0][q][0], m1v = lm_sm[X][1][q][0];
    const float m2v = lm_sm[X][2][q][0], m3v = lm_sm[X][3][q][0];
    const float M = fmaxf(fmaxf(m0v, m1v), fmaxf(m2v, m3v));
    const float w0 = __builtin_amdgcn_exp2f(m0v - M);
    const float w1 = __builtin_amdgcn_exp2f(m1v - M);
    const float w2 = __builtin_amdgcn_exp2f(m2v - M);
    const float w3 = __builtin_amdgcn_exp2f(m3v - M);
    const float L = w0 * lm_sm[X][0][q][1] + w1 * lm_sm[X][1][q][1] +
                    w2 * lm_sm[X][2][q][1] + w3 * lm_sm[X][3][q][1];
    const float inv = 1.0f / L;
    float rv[8];
#pragma unroll
    for (int j = 0; j < 8; ++j)
      rv[j] = (w0 * o_sm[X][0][q][h0 + j] + w1 * o_sm[X][1][q][h0 + j] +
               w2 * o_sm[X][2][q][h0 + j] + w3 * o_sm[X][3][q][h0 + j]) * inv;
    float* ob = out + ((size_t)(b * TS + t0X[X] + q)) * HS + h0;
    *(float4*)(ob)     = float4{rv[0], rv[1], rv[2], rv[3]};
    *(float4*)(ob + 4) = float4{rv[4], rv[5], rv[6], rv[7]};
  }
}

extern "C" void kernel_launch(void* const* d_in, const int* in_sizes, int n_in,
                              void* d_out, int out_size, void* d_ws, size_t ws_size,
                              hipStream_t stream) {
  const float* x  = (const float*)d_in[0];
  const float* Wk = (const float*)d_in[1];
  const float* Wq = (const float*)d_in[2];
  const float* Wv = (const float*)d_in[3];
  float* out = (float*)d_out;

  unsigned short* wT   = (unsigned short*)d_ws;
  unsigned short* q_ws = wT + 192 * 1024;
  unsigned short* k_ws = q_ws + (size_t)NROW * HS;
  unsigned short* vT   = k_ws + (size_t)NROW * HS;

  wt_kernel<<<dim3(768), dim3(256), 0, stream>>>(Wk, Wq, Wv, wT);
  qkv_kernel<<<dim3(NROW / 64), dim3(256), 0, stream>>>(x, wT, q_ws, k_ws, vT);
  attn_kernel<<<dim3(512), dim3(256), 0, stream>>>(q_ws, k_ws, vT, out);
}